// Round 1
// baseline (1455.492 us; speedup 1.0000x reference)
//
#include <hip/hip_runtime.h>
#include <math.h>

// ---------------------------------------------------------------------------
// SpatialGCN: 3 conv layers (edge-scatter with folded W_out) + edge MLP decode.
//
// Restructuring vs reference:
//  * per-edge contribution c[o] = sum_{h,c} relu(rel.Win+bin)[hc]*xj[c]*Wout[hc][o]
//    atomically added to dst (16 atomics/edge instead of 256).
//  * self-loops: rel==0 -> s=relu(b_in) constant -> folded into per-node
//    init:  out[i] = b_out + x[i] @ Wself,  Wself[c][o]=sum_h relu(bin[h*16+c])*Wout[h*16+c][o]
// ---------------------------------------------------------------------------

struct WPtrs {
    const float* bin0; const float* wout0;
    const float* bin1; const float* wout1;
    const float* bin2; const float* wout2;
};

// Extract packed pos (N x 2) and feat (N x 16) from x (N x 18).
__global__ __launch_bounds__(256) void prep_kernel(
    const float* __restrict__ x, float* __restrict__ pos,
    float* __restrict__ feat, int n)
{
    int i = blockIdx.x * 256 + threadIdx.x;
    if (i >= n) return;
    const float* r = x + (size_t)i * 18;
    float2 p; p.x = r[0]; p.y = r[1];
    ((float2*)pos)[i] = p;
    float4* fp = (float4*)feat + (size_t)i * 4;
    fp[0] = make_float4(r[2],  r[3],  r[4],  r[5]);
    fp[1] = make_float4(r[6],  r[7],  r[8],  r[9]);
    fp[2] = make_float4(r[10], r[11], r[12], r[13]);
    fp[3] = make_float4(r[14], r[15], r[16], r[17]);
}

// Wself[l][c*16+o] = sum_h relu(bin[h*16+c]) * Wout[(h*16+c)*16+o]
__global__ __launch_bounds__(256) void wself_kernel(WPtrs wp, float* __restrict__ wself)
{
    int l = blockIdx.x;
    const float* bin  = (l == 0) ? wp.bin0  : (l == 1) ? wp.bin1  : wp.bin2;
    const float* wout = (l == 0) ? wp.wout0 : (l == 1) ? wp.wout1 : wp.wout2;
    int t = threadIdx.x;          // t = c*16 + o
    int c = t >> 4, o = t & 15;
    float acc = 0.f;
    #pragma unroll
    for (int h = 0; h < 16; ++h) {
        int hc = h * 16 + c;
        acc += fmaxf(bin[hc], 0.f) * wout[hc * 16 + o];
    }
    wself[l * 256 + t] = acc;
}

// out[i] = b_out + in[i] @ Wself   (covers bias + self-loop contribution)
__global__ __launch_bounds__(256) void init_kernel(
    const float* __restrict__ in, const float* __restrict__ wself,
    const float* __restrict__ bout, float* __restrict__ out, int n)
{
    int i = blockIdx.x * 256 + threadIdx.x;
    bool valid = (i < n);
    int ii = valid ? i : 0;
    const float4* ip = (const float4*)in + (size_t)ii * 4;
    float4 a = ip[0], b = ip[1], c4 = ip[2], d4 = ip[3];
    float xin[16] = { a.x,a.y,a.z,a.w, b.x,b.y,b.z,b.w,
                      c4.x,c4.y,c4.z,c4.w, d4.x,d4.y,d4.z,d4.w };
    float acc[16];
    #pragma unroll
    for (int o = 0; o < 16; ++o) acc[o] = bout[o];
    #pragma unroll
    for (int c = 0; c < 16; ++c) {
        float t = xin[c];
        #pragma unroll
        for (int o = 0; o < 16; ++o)
            acc[o] = fmaf(t, wself[c * 16 + o], acc[o]);
    }
    if (valid) {
        float4* op = (float4*)out + (size_t)i * 4;
        op[0] = make_float4(acc[0],  acc[1],  acc[2],  acc[3]);
        op[1] = make_float4(acc[4],  acc[5],  acc[6],  acc[7]);
        op[2] = make_float4(acc[8],  acc[9],  acc[10], acc[11]);
        op[3] = make_float4(acc[12], acc[13], acc[14], acc[15]);
    }
}

// Per-edge: contrib = (relu(rel@Win+bin) * xj) @ Wout -> atomic add into out[dst].
__global__ __launch_bounds__(256) void edge_kernel(
    const int* __restrict__ ei,     // [2*E] src then dst
    const float* __restrict__ pos,  // [N,2]
    const float* __restrict__ feat, // [N,16]
    const float* __restrict__ Win,  // [2,256]
    const float* __restrict__ bin,  // [256]
    const float* __restrict__ Wout, // [256,16]
    float* __restrict__ out,        // [N,16]
    int E)
{
    int tid = blockIdx.x * 256 + threadIdx.x;
    bool valid = (tid < E);
    int e = valid ? tid : 0;
    int s = ei[e];
    int d = ei[E + e];

    float2 ps = ((const float2*)pos)[s];
    float2 pd = ((const float2*)pos)[d];
    float rx = ps.x - pd.x;
    float ry = ps.y - pd.y;

    const float4* fp = (const float4*)feat + (size_t)s * 4;
    float4 a = fp[0], b = fp[1], c4 = fp[2], d4 = fp[3];
    float xj[16] = { a.x,a.y,a.z,a.w, b.x,b.y,b.z,b.w,
                     c4.x,c4.y,c4.z,c4.w, d4.x,d4.y,d4.z,d4.w };

    float acc[16];
    #pragma unroll
    for (int o = 0; o < 16; ++o) acc[o] = 0.f;

    // weights are wave-uniform -> compiler should keep them in SGPRs (s_load)
    #pragma unroll 1
    for (int h = 0; h < 16; ++h) {
        #pragma unroll
        for (int c = 0; c < 16; ++c) {
            int hc = h * 16 + c;
            float sv = fmaf(rx, Win[hc], fmaf(ry, Win[256 + hc], bin[hc]));
            sv = fmaxf(sv, 0.f);
            float t = sv * xj[c];
            const float* wr = Wout + hc * 16;
            #pragma unroll
            for (int o = 0; o < 16; ++o)
                acc[o] = fmaf(t, wr[o], acc[o]);
        }
    }

    if (valid) {
        float* op = out + (size_t)d * 16;
        #pragma unroll
        for (int o = 0; o < 16; ++o)
            unsafeAtomicAdd(op + o, acc[o]);
    }
}

// Edge MLP: sigmoid(relu(relu([h_s,h_d]@Wd1+b1)@Wd2+b2)@Wd3+b3)
__global__ __launch_bounds__(256) void decode_kernel(
    const int* __restrict__ ei, const float* __restrict__ h,
    const float* __restrict__ Wd1, const float* __restrict__ bd1,
    const float* __restrict__ Wd2, const float* __restrict__ bd2,
    const float* __restrict__ Wd3, const float* __restrict__ bd3,
    float* __restrict__ out, int E)
{
    int tid = blockIdx.x * 256 + threadIdx.x;
    bool valid = (tid < E);
    int e = valid ? tid : 0;
    int s = ei[e];
    int d = ei[E + e];

    const float4* hp = (const float4*)h + (size_t)s * 4;
    float4 a = hp[0], b = hp[1], c4 = hp[2], d4 = hp[3];
    float hs[16] = { a.x,a.y,a.z,a.w, b.x,b.y,b.z,b.w,
                     c4.x,c4.y,c4.z,c4.w, d4.x,d4.y,d4.z,d4.w };
    const float4* hq = (const float4*)h + (size_t)d * 4;
    float4 e0 = hq[0], e1 = hq[1], e2 = hq[2], e3 = hq[3];
    float hd[16] = { e0.x,e0.y,e0.z,e0.w, e1.x,e1.y,e1.z,e1.w,
                     e2.x,e2.y,e2.z,e2.w, e3.x,e3.y,e3.z,e3.w };

    float z1[16];
    #pragma unroll
    for (int o = 0; o < 16; ++o) z1[o] = bd1[o];
    #pragma unroll
    for (int c = 0; c < 16; ++c) {
        float u = hs[c], v = hd[c];
        #pragma unroll
        for (int o = 0; o < 16; ++o)
            z1[o] = fmaf(u, Wd1[c * 16 + o], fmaf(v, Wd1[(16 + c) * 16 + o], z1[o]));
    }

    float z2[16];
    #pragma unroll
    for (int o = 0; o < 16; ++o) z2[o] = bd2[o];
    #pragma unroll
    for (int c = 0; c < 16; ++c) {
        float t = fmaxf(z1[c], 0.f);
        #pragma unroll
        for (int o = 0; o < 16; ++o)
            z2[o] = fmaf(t, Wd2[c * 16 + o], z2[o]);
    }

    float y = bd3[0];
    #pragma unroll
    for (int c = 0; c < 16; ++c)
        y = fmaf(fmaxf(z2[c], 0.f), Wd3[c], y);

    if (valid)
        out[tid] = 1.f / (1.f + expf(-y));
}

extern "C" void kernel_launch(void* const* d_in, const int* in_sizes, int n_in,
                              void* d_out, int out_size, void* d_ws, size_t ws_size,
                              hipStream_t stream)
{
    const float* x     = (const float*)d_in[0];
    const int*   ei    = (const int*)  d_in[1];
    const float* Win1  = (const float*)d_in[2];
    const float* bin1  = (const float*)d_in[3];
    const float* Wout1 = (const float*)d_in[4];
    const float* bout1 = (const float*)d_in[5];
    const float* Win2  = (const float*)d_in[6];
    const float* bin2  = (const float*)d_in[7];
    const float* Wout2 = (const float*)d_in[8];
    const float* bout2 = (const float*)d_in[9];
    const float* Win3  = (const float*)d_in[10];
    const float* bin3  = (const float*)d_in[11];
    const float* Wout3 = (const float*)d_in[12];
    const float* bout3 = (const float*)d_in[13];
    const float* Wd1   = (const float*)d_in[14];
    const float* bd1   = (const float*)d_in[15];
    const float* Wd2   = (const float*)d_in[16];
    const float* bd2   = (const float*)d_in[17];
    const float* Wd3   = (const float*)d_in[18];
    const float* bd3   = (const float*)d_in[19];

    int n = in_sizes[0] / 18;
    int E = in_sizes[1] / 2;

    float* ws    = (float*)d_ws;
    float* pos   = ws;                  // n*2
    float* feat  = pos  + (size_t)2 * n;  // n*16
    float* hA    = feat + (size_t)16 * n; // n*16
    float* hB    = hA   + (size_t)16 * n; // n*16
    float* wself = hB   + (size_t)16 * n; // 3*256
    float* outp  = (float*)d_out;

    int nb_n = (n + 255) / 256;
    int nb_e = (E + 255) / 256;

    prep_kernel<<<nb_n, 256, 0, stream>>>(x, pos, feat, n);

    WPtrs wp { bin1, Wout1, bin2, Wout2, bin3, Wout3 };
    wself_kernel<<<3, 256, 0, stream>>>(wp, wself);

    // Layer 1: feat -> hA
    init_kernel<<<nb_n, 256, 0, stream>>>(feat, wself + 0,   bout1, hA, n);
    edge_kernel<<<nb_e, 256, 0, stream>>>(ei, pos, feat, Win1, bin1, Wout1, hA, E);
    // Layer 2: hA -> hB
    init_kernel<<<nb_n, 256, 0, stream>>>(hA,   wself + 256, bout2, hB, n);
    edge_kernel<<<nb_e, 256, 0, stream>>>(ei, pos, hA,   Win2, bin2, Wout2, hB, E);
    // Layer 3: hB -> hA
    init_kernel<<<nb_n, 256, 0, stream>>>(hB,   wself + 512, bout3, hA, n);
    edge_kernel<<<nb_e, 256, 0, stream>>>(ei, pos, hB,   Win3, bin3, Wout3, hA, E);

    // Decode on original E edges
    decode_kernel<<<nb_e, 256, 0, stream>>>(ei, hA, Wd1, bd1, Wd2, bd2, Wd3, bd3,
                                            outp, E);
}